// Round 9
// baseline (237.460 us; speedup 1.0000x reference)
//
#include <hip/hip_runtime.h>

constexpr int NTOT   = 13;
constexpr int DIM    = 1 << NTOT;   // 8192
constexpr int DDATA  = DIM / 2;     // 4096
constexpr int LAYERS = 6;
constexpr int NGATES = LAYERS * NTOT; // 78
constexpr int BLOCK  = 512;         // 8 waves; 16 amps/thread

// Per-gate coefficients from params.
// U = RY@RX = [[A+iB, -C-iD], [C-iD, A-iB]], A=cy*cx, B=sy*sx, C=sy*cx, D=cy*sx.
__global__ void gates_precompute(const float* __restrict__ params,
                                 float* __restrict__ gates) {
    int t = threadIdx.x;
    if (t >= NGATES) return;
    int l = t / NTOT, q = t % NTOT;
    float tx = params[2 * NTOT * l + q];
    float ty = params[2 * NTOT * l + NTOT + q];
    float sx, cx, sy, cy;
    sincosf(0.5f * tx, &sx, &cx);
    sincosf(0.5f * ty, &sy, &cy);
    gates[4 * t + 0] = cy * cx;
    gates[4 * t + 1] = sy * sx;
    gates[4 * t + 2] = sy * cx;
    gates[4 * t + 3] = cy * sx;
}

// Fixed storage map: amplitude idx lives at s[phi(idx)], phi(idx)=idx^((idx>>4)&15).
// Desk-checked: init-write, layout-A (idx=m<<9|L<<3|w) and layout-B (idx=w<<10|L<<4|m)
// all hit each 8B bank-pair exactly 4x per wave (the ds_*_b64 minimum).
__device__ __forceinline__ int phi(int idx) { return idx ^ ((idx >> 4) & 15); }

__device__ __forceinline__ void gate_pair(float2& va, float2& vb,
                                          float A, float B, float C, float D) {
    float ar = va.x, ai = va.y, br = vb.x, bi = vb.y;
    va.x = A * ar - B * ai - C * br + D * bi;
    va.y = B * ar + A * ai - D * br - C * bi;
    vb.x = C * ar + D * ai + A * br + B * bi;
    vb.y = C * ai - D * ar + A * bi - B * br;
}

__global__ __launch_bounds__(BLOCK, 4)
void qddpm_main(const float* __restrict__ re_in, const float* __restrict__ im_in,
                const int* __restrict__ m_res, const float* __restrict__ g,
                float* __restrict__ out) {
    __shared__ float2 s[DIM];          // 64 KB
    const int b = blockIdx.x;
    const int t = threadIdx.x;
    const int L = t & 63;              // lane
    const int w = t >> 6;              // wave 0..7

    // ---- global -> LDS at phi(idx), coalesced float4 loads
    const float4* re4 = reinterpret_cast<const float4*>(re_in + (size_t)b * DIM);
    const float4* im4 = reinterpret_cast<const float4*>(im_in + (size_t)b * DIM);
    #pragma unroll
    for (int k = 0; k < 4; ++k) {
        int e = t + k * BLOCK;         // float4 index 0..2047
        float4 r = re4[e];
        float4 i = im4[e];
        s[phi(4 * e + 0)] = make_float2(r.x, i.x);
        s[phi(4 * e + 1)] = make_float2(r.y, i.y);
        s[phi(4 * e + 2)] = make_float2(r.z, i.z);
        s[phi(4 * e + 3)] = make_float2(r.w, i.w);
    }
    __syncthreads();

    // Layout A: idx = (m<<9)|(L<<3)|w. phi alters only bits[3:0] (by L[4:1]),
    // so cell(m) = phi(baseA) + (m<<9): one addr reg + compile-time offsets.
    const int baseA = (L << 3) | w;
    const int addrA = phi(baseA);
    // Layout B: idx = (w<<10)|(L<<4)|m. phi: low4 ^= L[3:0].
    const int baseB = (w << 10) | (L << 4);
    int addrB[16];
    #pragma unroll
    for (int m = 0; m < 16; ++m) addrB[m] = baseB | (m ^ (L & 15));

    float2 v[16];

    for (int l = 0; l < LAYERS; ++l) {
        const float* gl = g + 4 * NTOT * l;

        // READ_A (thread-private cells; RMW => no barrier before WRITE_A)
        #pragma unroll
        for (int m = 0; m < 16; ++m) v[m] = s[addrA + (m << 9)];

        // q0..q3: register bits (idx bits 12..9 = m bits 3..0)
        #pragma unroll
        for (int q = 0; q < 4; ++q) {
            const float A = gl[4 * q], B = gl[4 * q + 1];
            const float C = gl[4 * q + 2], D = gl[4 * q + 3];
            const int bit = 8 >> q;
            #pragma unroll
            for (int m = 0; m < 16; ++m)
                if (!(m & bit)) gate_pair(v[m], v[m | bit], A, B, C, D);
        }

        // q4..q8: lane bits (idx bit 12-q = L bit 9-q), partner via shfl_xor.
        // bit=0 amp: new = (A+iB)v + (-C-iD)p ; bit=1 amp: new = (C-iD)p + (A-iB)v
        #pragma unroll
        for (int q = 4; q < 9; ++q) {
            const float A = gl[4 * q], B = gl[4 * q + 1];
            const float C = gl[4 * q + 2], D = gl[4 * q + 3];
            const int sh = 9 - q;            // L bit position: 5,4,3,2,1
            const int xm = 1 << sh;          // 32,16,8,4,2
            const int bit = (L >> sh) & 1;
            const float Bs = bit ? -B : B;
            const float Cq = bit ? C : -C;
            #pragma unroll
            for (int m = 0; m < 16; ++m) {
                float vr = v[m].x, vi = v[m].y;
                float pr = __shfl_xor(vr, xm, 64);
                float pi = __shfl_xor(vi, xm, 64);
                v[m].x = A * vr - Bs * vi + Cq * pr + D * pi;
                v[m].y = A * vi + Bs * vr + Cq * pi - D * pr;
            }
        }

        // WRITE_A (same cells) -> barrier -> READ_B
        #pragma unroll
        for (int m = 0; m < 16; ++m) s[addrA + (m << 9)] = v[m];
        __syncthreads();
        #pragma unroll
        for (int m = 0; m < 16; ++m) v[m] = s[addrB[m]];

        // q9..q12: register bits in layout B (idx bits 3..0 = m bits 3..0)
        #pragma unroll
        for (int q = 9; q < 13; ++q) {
            const float A = gl[4 * q], B = gl[4 * q + 1];
            const float C = gl[4 * q + 2], D = gl[4 * q + 3];
            const int bit = 8 >> (q - 9);
            #pragma unroll
            for (int m = 0; m < 16; ++m)
                if (!(m & bit)) gate_pair(v[m], v[m | bit], A, B, C, D);
        }

        // brickwork-CZ sign: (-1)^popc(idx & idx>>1), idx = baseB|m
        #pragma unroll
        for (int m = 0; m < 16; ++m) {
            int idx = baseB | m;
            float sg = 1.0f - 2.0f * (float)(__popc(idx & (idx >> 1)) & 1);
            v[m].x *= sg;
            v[m].y *= sg;
        }

        if (l < LAYERS - 1) {
            // WRITE_B (same cells RMW) -> barrier -> next layer's READ_A
            #pragma unroll
            for (int m = 0; m < 16; ++m) s[addrB[m]] = v[m];
            __syncthreads();
        }
    }

    // ---- epilogue directly from layout-B registers (idx bit12 = w bit2 = ancilla)
    const int keep = (m_res[b] != 0) ? 1 : 0;
    const bool mine = ((w >> 2) & 1) == keep;
    float acc = 0.0f;
    #pragma unroll
    for (int m = 0; m < 16; ++m) acc += v[m].x * v[m].x + v[m].y * v[m].y;
    #pragma unroll
    for (int o = 32; o > 0; o >>= 1) acc += __shfl_down(acc, o, 64);
    __syncthreads();                    // all READ_Bs done; LDS reusable as scratch
    float* red = reinterpret_cast<float*>(s);
    if (L == 0) red[w] = acc;
    __syncthreads();
    const float tot = red[keep * 4 + 0] + red[keep * 4 + 1]
                    + red[keep * 4 + 2] + red[keep * 4 + 3];
    const float sc = rsqrtf(tot);
    if (mine) {
        const int j = ((w & 3) << 10) | (L << 4);   // output data index base (+m)
        float4* o4 = reinterpret_cast<float4*>(out + (size_t)b * DDATA * 2 + (size_t)j * 2);
        #pragma unroll
        for (int m = 0; m < 8; ++m)
            o4[m] = make_float4(v[2 * m].x * sc, v[2 * m].y * sc,
                                v[2 * m + 1].x * sc, v[2 * m + 1].y * sc);
    }
}

extern "C" void kernel_launch(void* const* d_in, const int* in_sizes, int n_in,
                              void* d_out, int out_size, void* d_ws, size_t ws_size,
                              hipStream_t stream) {
    const float* re     = (const float*)d_in[0];
    const float* im     = (const float*)d_in[1];
    const float* params = (const float*)d_in[2];
    const int*   mres   = (const int*)d_in[3];
    float* out   = (float*)d_out;
    float* gates = (float*)d_ws;   // 78*4 floats = 1248 B

    const int B = in_sizes[3];     // 512

    gates_precompute<<<1, 128, 0, stream>>>(params, gates);
    qddpm_main<<<B, BLOCK, 0, stream>>>(re, im, mres, gates, out);
}

// Round 11
// 217.778 us; speedup vs baseline: 1.0904x; 1.0904x over previous
//
#include <hip/hip_runtime.h>

constexpr int NTOT   = 13;
constexpr int DIM    = 1 << NTOT;   // 8192
constexpr int DDATA  = DIM / 2;     // 4096
constexpr int LAYERS = 6;
constexpr int NGATES = LAYERS * NTOT; // 78
constexpr int BLOCK  = 512;         // 8 waves; 16 amps/thread

// Per-gate coefficients from params.
// U = RY@RX = [[A+iB, -C-iD], [C-iD, A-iB]], A=cy*cx, B=sy*sx, C=sy*cx, D=cy*sx.
__global__ void gates_precompute(const float* __restrict__ params,
                                 float* __restrict__ gates) {
    int t = threadIdx.x;
    if (t >= NGATES) return;
    int l = t / NTOT, q = t % NTOT;
    float tx = params[2 * NTOT * l + q];
    float ty = params[2 * NTOT * l + NTOT + q];
    float sx, cx, sy, cy;
    sincosf(0.5f * tx, &sx, &cx);
    sincosf(0.5f * ty, &sy, &cy);
    gates[4 * t + 0] = cy * cx;
    gates[4 * t + 1] = sy * sx;
    gates[4 * t + 2] = sy * cx;
    gates[4 * t + 3] = cy * sx;
}

// Fixed storage map: amplitude idx lives at s[phi(idx)], phi(idx)=idx^((idx>>4)&15).
// Conflict-free (4 lanes/bank-pair, the ds_*_b64 minimum) for init-write,
// layout-A (idx=m<<9|L<<3|w) and layout-B (idx=w<<10|L<<4|m) access patterns.
__device__ __forceinline__ int phi(int idx) { return idx ^ ((idx >> 4) & 15); }

__device__ __forceinline__ void gate_pair(float2& va, float2& vb,
                                          float A, float B, float C, float D) {
    float ar = va.x, ai = va.y, br = vb.x, bi = vb.y;
    va.x = A * ar - B * ai - C * br + D * bi;
    va.y = B * ar + A * ai - D * br - C * bi;
    vb.x = C * ar + D * ai + A * br + B * bi;
    vb.y = C * ai - D * ar + A * bi - B * br;
}

// Second launch-bounds arg = 2: under "blocks/CU" semantics -> 4 waves/EU -> 128-VGPR
// cap; under "waves/EU" semantics -> 256-VGPR cap. Either way no 64-VGPR starvation
// (R3's spill cause: ",4" produced a 64-VGPR cap -> 200B/thread scratch traffic).
__global__ __launch_bounds__(BLOCK, 2)
void qddpm_main(const float* __restrict__ re_in, const float* __restrict__ im_in,
                const int* __restrict__ m_res, const float* __restrict__ g,
                float* __restrict__ out) {
    __shared__ float2 s[DIM];              // 64 KB
    __shared__ float  gsh[NGATES * 4];     // 1.25 KB: all gate coefficients
    __shared__ float  red[8];              // per-wave norm partials
    const int b = blockIdx.x;
    const int t = threadIdx.x;
    const int L = t & 63;              // lane
    const int w = t >> 6;              // wave 0..7

    if (t < NGATES * 4) gsh[t] = g[t];

    // ---- global -> LDS at phi(idx), coalesced float4 loads
    const float4* re4 = reinterpret_cast<const float4*>(re_in + (size_t)b * DIM);
    const float4* im4 = reinterpret_cast<const float4*>(im_in + (size_t)b * DIM);
    #pragma unroll
    for (int k = 0; k < 4; ++k) {
        int e = t + k * BLOCK;         // float4 index 0..2047
        float4 r = re4[e];
        float4 i = im4[e];
        s[phi(4 * e + 0)] = make_float2(r.x, i.x);
        s[phi(4 * e + 1)] = make_float2(r.y, i.y);
        s[phi(4 * e + 2)] = make_float2(r.z, i.z);
        s[phi(4 * e + 3)] = make_float2(r.w, i.w);
    }
    __syncthreads();

    // Layout A: idx = (m<<9)|(L<<3)|w. phi alters only bits[3:0] (by L[4:1]),
    // so cell(m) = phi(baseA) + (m<<9): one addr reg, offsets fold into ds imm.
    const int addrA = phi((L << 3) | w);
    // Layout B: idx = (w<<10)|(L<<4)|m. baseB low4 = 0, so
    // addrB(m) = baseB | (m ^ (L&15)) = (baseB ^ (L&15)) ^ m: one base reg + XOR.
    const int baseB  = (w << 10) | (L << 4);
    const int addrB0 = baseB ^ (L & 15);

    float2 v[16];

    for (int l = 0; l < LAYERS; ++l) {
        const float* gl = gsh + 4 * NTOT * l;

        // READ_A (thread-private cells; RMW => no barrier before WRITE_A)
        #pragma unroll
        for (int m = 0; m < 16; ++m) v[m] = s[addrA + (m << 9)];

        // q0..q3: register bits (idx bits 12..9 = m bits 3..0)
        #pragma unroll
        for (int q = 0; q < 4; ++q) {
            const float A = gl[4 * q], B = gl[4 * q + 1];
            const float C = gl[4 * q + 2], D = gl[4 * q + 3];
            const int bit = 8 >> q;
            #pragma unroll
            for (int m = 0; m < 16; ++m)
                if (!(m & bit)) gate_pair(v[m], v[m | bit], A, B, C, D);
        }

        // q4..q8: lane bits (idx bit 12-q = L bit 9-q), partner via shfl_xor.
        // bit=0 amp: new = (A+iB)v + (-C-iD)p ; bit=1 amp: new = (C-iD)p + (A-iB)v
        #pragma unroll
        for (int q = 4; q < 9; ++q) {
            const float A = gl[4 * q], B = gl[4 * q + 1];
            const float C = gl[4 * q + 2], D = gl[4 * q + 3];
            const int sh = 9 - q;            // L bit position: 5,4,3,2,1
            const int xm = 1 << sh;          // 32,16,8,4,2
            const int bit = (L >> sh) & 1;
            const float Bs = bit ? -B : B;
            const float Cq = bit ? C : -C;
            #pragma unroll
            for (int m = 0; m < 16; ++m) {
                float vr = v[m].x, vi = v[m].y;
                float pr = __shfl_xor(vr, xm, 64);
                float pi = __shfl_xor(vi, xm, 64);
                v[m].x = A * vr - Bs * vi + Cq * pr + D * pi;
                v[m].y = A * vi + Bs * vr + Cq * pi - D * pr;
            }
        }

        // WRITE_A (same cells) -> barrier -> READ_B
        #pragma unroll
        for (int m = 0; m < 16; ++m) s[addrA + (m << 9)] = v[m];
        __syncthreads();
        #pragma unroll
        for (int m = 0; m < 16; ++m) v[m] = s[addrB0 ^ m];

        // q9..q12: register bits in layout B (idx bits 3..0 = m bits 3..0)
        #pragma unroll
        for (int q = 9; q < 13; ++q) {
            const float A = gl[4 * q], B = gl[4 * q + 1];
            const float C = gl[4 * q + 2], D = gl[4 * q + 3];
            const int bit = 8 >> (q - 9);
            #pragma unroll
            for (int m = 0; m < 16; ++m)
                if (!(m & bit)) gate_pair(v[m], v[m | bit], A, B, C, D);
        }

        // brickwork-CZ sign: (-1)^popc(idx & idx>>1), idx = baseB|m
        #pragma unroll
        for (int m = 0; m < 16; ++m) {
            int idx = baseB | m;
            float sg = 1.0f - 2.0f * (float)(__popc(idx & (idx >> 1)) & 1);
            v[m].x *= sg;
            v[m].y *= sg;
        }

        if (l < LAYERS - 1) {
            // WRITE_B (same cells RMW) -> barrier -> next layer's READ_A
            #pragma unroll
            for (int m = 0; m < 16; ++m) s[addrB0 ^ m] = v[m];
            __syncthreads();
        }
    }

    // ---- epilogue directly from layout-B registers (idx bit12 = w bit2 = ancilla)
    const int keep = (m_res[b] != 0) ? 1 : 0;
    const bool mine = ((w >> 2) & 1) == keep;
    float acc = 0.0f;
    #pragma unroll
    for (int m = 0; m < 16; ++m) acc += v[m].x * v[m].x + v[m].y * v[m].y;
    #pragma unroll
    for (int o = 32; o > 0; o >>= 1) acc += __shfl_down(acc, o, 64);
    if (L == 0) red[w] = acc;
    __syncthreads();
    const float tot = red[keep * 4 + 0] + red[keep * 4 + 1]
                    + red[keep * 4 + 2] + red[keep * 4 + 3];
    const float sc = rsqrtf(tot);
    if (mine) {
        const int j = ((w & 3) << 10) | (L << 4);   // output data index base (+m)
        float4* o4 = reinterpret_cast<float4*>(out + (size_t)b * DDATA * 2 + (size_t)j * 2);
        #pragma unroll
        for (int m = 0; m < 8; ++m)
            o4[m] = make_float4(v[2 * m].x * sc, v[2 * m].y * sc,
                                v[2 * m + 1].x * sc, v[2 * m + 1].y * sc);
    }
}

extern "C" void kernel_launch(void* const* d_in, const int* in_sizes, int n_in,
                              void* d_out, int out_size, void* d_ws, size_t ws_size,
                              hipStream_t stream) {
    const float* re     = (const float*)d_in[0];
    const float* im     = (const float*)d_in[1];
    const float* params = (const float*)d_in[2];
    const int*   mres   = (const int*)d_in[3];
    float* out   = (float*)d_out;
    float* gates = (float*)d_ws;   // 78*4 floats = 1248 B

    const int B = in_sizes[3];     // 512

    gates_precompute<<<1, 128, 0, stream>>>(params, gates);
    qddpm_main<<<B, BLOCK, 0, stream>>>(re, im, mres, gates, out);
}

// Round 12
// 209.713 us; speedup vs baseline: 1.1323x; 1.0385x over previous
//
#include <hip/hip_runtime.h>

constexpr int NTOT   = 13;
constexpr int DIM    = 1 << NTOT;   // 8192
constexpr int DDATA  = DIM / 2;     // 4096
constexpr int LAYERS = 6;
constexpr int NGATES = LAYERS * NTOT; // 78
constexpr int BLOCK  = 512;         // 8 waves; 16 amps/thread

// Per-gate coefficients from params.
// U = RY@RX = [[A+iB, -C-iD], [C-iD, A-iB]], A=cy*cx, B=sy*sx, C=sy*cx, D=cy*sx.
__global__ void gates_precompute(const float* __restrict__ params,
                                 float* __restrict__ gates) {
    int t = threadIdx.x;
    if (t >= NGATES) return;
    int l = t / NTOT, q = t % NTOT;
    float tx = params[2 * NTOT * l + q];
    float ty = params[2 * NTOT * l + NTOT + q];
    float sx, cx, sy, cy;
    sincosf(0.5f * tx, &sx, &cx);
    sincosf(0.5f * ty, &sy, &cy);
    gates[4 * t + 0] = cy * cx;
    gates[4 * t + 1] = sy * sx;
    gates[4 * t + 2] = sy * cx;
    gates[4 * t + 3] = cy * sx;
}

// Fixed storage map: amplitude idx lives at s[phi(idx)], phi(idx)=idx^((idx>>4)&15).
// Conflict-free (4 lanes/bank-pair, the ds_*_b64 minimum) for init-write,
// layout-A (idx=m<<9|L<<3|w) and layout-B (idx=w<<10|L<<4|m) access patterns.
__device__ __forceinline__ int phi(int idx) { return idx ^ ((idx >> 4) & 15); }

__device__ __forceinline__ void gate_pair(float2& va, float2& vb,
                                          float A, float B, float C, float D) {
    float ar = va.x, ai = va.y, br = vb.x, bi = vb.y;
    va.x = A * ar - B * ai - C * br + D * bi;
    va.y = B * ar + A * ai - D * br - C * bi;
    vb.x = C * ar + D * ai + A * br + B * bi;
    vb.y = C * ai - D * ar + A * bi - B * br;
}

// LDS must stay EXACTLY 64 KB: measured occupancy shows the schedulable LDS pool
// is ~128 KB/CU (2x65536 fits -> 2 blocks/CU; 2x67072 does not -> 1 block/CU).
__global__ __launch_bounds__(BLOCK, 2)
void qddpm_main(const float* __restrict__ re_in, const float* __restrict__ im_in,
                const int* __restrict__ m_res, const float* __restrict__ g,
                float* __restrict__ out) {
    __shared__ float2 s[DIM];          // exactly 65536 B, nothing else in LDS
    const int b = blockIdx.x;
    const int t = threadIdx.x;
    const int L = t & 63;              // lane
    const int w = t >> 6;              // wave 0..7

    // ---- global -> LDS at phi(idx), coalesced float4 loads
    const float4* re4 = reinterpret_cast<const float4*>(re_in + (size_t)b * DIM);
    const float4* im4 = reinterpret_cast<const float4*>(im_in + (size_t)b * DIM);
    #pragma unroll
    for (int k = 0; k < 4; ++k) {
        int e = t + k * BLOCK;         // float4 index 0..2047
        float4 r = re4[e];
        float4 i = im4[e];
        s[phi(4 * e + 0)] = make_float2(r.x, i.x);
        s[phi(4 * e + 1)] = make_float2(r.y, i.y);
        s[phi(4 * e + 2)] = make_float2(r.z, i.z);
        s[phi(4 * e + 3)] = make_float2(r.w, i.w);
    }
    __syncthreads();

    // Layout A: idx = (m<<9)|(L<<3)|w -> cell(m) = phi(baseA) + (m<<9).
    const int addrA = phi((L << 3) | w);
    // Layout B: idx = (w<<10)|(L<<4)|m -> cell(m) = (baseB ^ (L&15)) ^ m.
    const int baseB  = (w << 10) | (L << 4);
    const int addrB0 = baseB ^ (L & 15);

    // Precomputed ds_bpermute lane addresses for the 5 exchange masks.
    int bpa[5];
    #pragma unroll
    for (int q = 0; q < 5; ++q) bpa[q] = (L ^ (32 >> q)) << 2;

    float2 v[16];

    for (int l = 0; l < LAYERS; ++l) {
        const float* gl = g + 4 * NTOT * l;   // wave-uniform -> s_load

        // READ_A (thread-private cells; RMW => no barrier before WRITE_A)
        #pragma unroll
        for (int m = 0; m < 16; ++m) v[m] = s[addrA + (m << 9)];

        // q0..q3: register bits (idx bits 12..9 = m bits 3..0)
        #pragma unroll
        for (int q = 0; q < 4; ++q) {
            const float A = gl[4 * q], B = gl[4 * q + 1];
            const float C = gl[4 * q + 2], D = gl[4 * q + 3];
            const int bit = 8 >> q;
            #pragma unroll
            for (int m = 0; m < 16; ++m)
                if (!(m & bit)) gate_pair(v[m], v[m | bit], A, B, C, D);
        }

        // q4..q8: lane bits (idx bit 12-q = L bit 9-q), partner via ds_bpermute.
        // bit=0 amp: new = (A+iB)v + (-C-iD)p ; bit=1 amp: new = (C-iD)p + (A-iB)v
        #pragma unroll
        for (int q = 4; q < 9; ++q) {
            const float A = gl[4 * q], B = gl[4 * q + 1];
            const float C = gl[4 * q + 2], D = gl[4 * q + 3];
            const int sh = 9 - q;            // L bit position: 5,4,3,2,1
            const int bit = (L >> sh) & 1;
            const int ba  = bpa[q - 4];
            const float Bs = bit ? -B : B;
            const float Cq = bit ? C : -C;
            #pragma unroll
            for (int m = 0; m < 16; ++m) {
                float vr = v[m].x, vi = v[m].y;
                float pr = __int_as_float(__builtin_amdgcn_ds_bpermute(ba, __float_as_int(vr)));
                float pi = __int_as_float(__builtin_amdgcn_ds_bpermute(ba, __float_as_int(vi)));
                v[m].x = A * vr - Bs * vi + Cq * pr + D * pi;
                v[m].y = A * vi + Bs * vr + Cq * pi - D * pr;
            }
        }

        // WRITE_A (same cells) -> barrier -> READ_B
        #pragma unroll
        for (int m = 0; m < 16; ++m) s[addrA + (m << 9)] = v[m];
        __syncthreads();
        #pragma unroll
        for (int m = 0; m < 16; ++m) v[m] = s[addrB0 ^ m];

        // q9..q12: register bits in layout B (idx bits 3..0 = m bits 3..0)
        #pragma unroll
        for (int q = 9; q < 13; ++q) {
            const float A = gl[4 * q], B = gl[4 * q + 1];
            const float C = gl[4 * q + 2], D = gl[4 * q + 3];
            const int bit = 8 >> (q - 9);
            #pragma unroll
            for (int m = 0; m < 16; ++m)
                if (!(m & bit)) gate_pair(v[m], v[m | bit], A, B, C, D);
        }

        // brickwork-CZ sign: (-1)^popc(idx & idx>>1), idx = baseB|m
        #pragma unroll
        for (int m = 0; m < 16; ++m) {
            int idx = baseB | m;
            float sg = 1.0f - 2.0f * (float)(__popc(idx & (idx >> 1)) & 1);
            v[m].x *= sg;
            v[m].y *= sg;
        }

        if (l < LAYERS - 1) {
            // WRITE_B (same cells RMW) -> barrier -> next layer's READ_A
            #pragma unroll
            for (int m = 0; m < 16; ++m) s[addrB0 ^ m] = v[m];
            __syncthreads();
        }
    }

    // ---- epilogue directly from layout-B registers (idx bit12 = w bit2 = ancilla)
    const int keep = (m_res[b] != 0) ? 1 : 0;
    const bool mine = ((w >> 2) & 1) == keep;
    float acc = 0.0f;
    #pragma unroll
    for (int m = 0; m < 16; ++m) acc += v[m].x * v[m].x + v[m].y * v[m].y;
    #pragma unroll
    for (int o = 32; o > 0; o >>= 1) acc += __shfl_down(acc, o, 64);
    __syncthreads();                    // all READ_Bs done; s[] reusable as scratch
    float* red = reinterpret_cast<float*>(s);
    if (L == 0) red[w] = acc;
    __syncthreads();
    const float tot = red[keep * 4 + 0] + red[keep * 4 + 1]
                    + red[keep * 4 + 2] + red[keep * 4 + 3];
    const float sc = rsqrtf(tot);
    if (mine) {
        const int j = ((w & 3) << 10) | (L << 4);   // output data index base (+m)
        float4* o4 = reinterpret_cast<float4*>(out + (size_t)b * DDATA * 2 + (size_t)j * 2);
        #pragma unroll
        for (int m = 0; m < 8; ++m)
            o4[m] = make_float4(v[2 * m].x * sc, v[2 * m].y * sc,
                                v[2 * m + 1].x * sc, v[2 * m + 1].y * sc);
    }
}

extern "C" void kernel_launch(void* const* d_in, const int* in_sizes, int n_in,
                              void* d_out, int out_size, void* d_ws, size_t ws_size,
                              hipStream_t stream) {
    const float* re     = (const float*)d_in[0];
    const float* im     = (const float*)d_in[1];
    const float* params = (const float*)d_in[2];
    const int*   mres   = (const int*)d_in[3];
    float* out   = (float*)d_out;
    float* gates = (float*)d_ws;   // 78*4 floats = 1248 B

    const int B = in_sizes[3];     // 512

    gates_precompute<<<1, 128, 0, stream>>>(params, gates);
    qddpm_main<<<B, BLOCK, 0, stream>>>(re, im, mres, gates, out);
}

// Round 13
// 208.101 us; speedup vs baseline: 1.1411x; 1.0077x over previous
//
#include <hip/hip_runtime.h>

constexpr int NTOT   = 13;
constexpr int DIM    = 1 << NTOT;   // 8192
constexpr int DDATA  = DIM / 2;     // 4096
constexpr int LAYERS = 6;
constexpr int NGATES = LAYERS * NTOT; // 78
constexpr int BLOCK  = 512;         // 8 waves; 16 amps/thread

// Per-gate coefficients from params.
// U = RY@RX = [[A+iB, -C-iD], [C-iD, A-iB]], A=cy*cx, B=sy*sx, C=sy*cx, D=cy*sx.
__global__ void gates_precompute(const float* __restrict__ params,
                                 float* __restrict__ gates) {
    int t = threadIdx.x;
    if (t >= NGATES) return;
    int l = t / NTOT, q = t % NTOT;
    float tx = params[2 * NTOT * l + q];
    float ty = params[2 * NTOT * l + NTOT + q];
    float sx, cx, sy, cy;
    sincosf(0.5f * tx, &sx, &cx);
    sincosf(0.5f * ty, &sy, &cy);
    gates[4 * t + 0] = cy * cx;
    gates[4 * t + 1] = sy * sx;
    gates[4 * t + 2] = sy * cx;
    gates[4 * t + 3] = cy * sx;
}

// Fixed storage map: amplitude idx lives at s[phi(idx)], phi(idx)=idx^((idx>>4)&15).
// Conflict-free (4 lanes/bank-pair, the ds_*_b64 minimum) for init-write,
// layout-A (idx=m<<9|L<<3|w) and layout-B (idx=w<<10|L<<4|m) access patterns.
__device__ __forceinline__ int phi(int idx) { return idx ^ ((idx >> 4) & 15); }

__device__ __forceinline__ void gate_pair(float2& va, float2& vb,
                                          float A, float B, float C, float D) {
    float ar = va.x, ai = va.y, br = vb.x, bi = vb.y;
    va.x = A * ar - B * ai - C * br + D * bi;
    va.y = B * ar + A * ai - D * br - C * bi;
    vb.x = C * ar + D * ai + A * br + B * bi;
    vb.y = C * ai - D * ar + A * bi - B * br;
}

// __launch_bounds__: SINGLE arg only. Measured across R9/R11/R12: runtime
// waves/SIMD == the second arg (amdgpu-waves-per-eu pins occupancy), so any
// second arg hard-caps residency. Without it: LDS-limited 2 blocks/CU.
__global__ __launch_bounds__(BLOCK)
void qddpm_main(const float* __restrict__ re_in, const float* __restrict__ im_in,
                const int* __restrict__ m_res, const float* __restrict__ g,
                float* __restrict__ out) {
    __shared__ float2 s[DIM];          // exactly 65536 B, nothing else in LDS
    const int b = blockIdx.x;
    const int t = threadIdx.x;
    const int L = t & 63;              // lane
    const int w = t >> 6;              // wave 0..7

    // ---- global -> LDS at phi(idx), coalesced float4 loads
    const float4* re4 = reinterpret_cast<const float4*>(re_in + (size_t)b * DIM);
    const float4* im4 = reinterpret_cast<const float4*>(im_in + (size_t)b * DIM);
    #pragma unroll
    for (int k = 0; k < 4; ++k) {
        int e = t + k * BLOCK;         // float4 index 0..2047
        float4 r = re4[e];
        float4 i = im4[e];
        s[phi(4 * e + 0)] = make_float2(r.x, i.x);
        s[phi(4 * e + 1)] = make_float2(r.y, i.y);
        s[phi(4 * e + 2)] = make_float2(r.z, i.z);
        s[phi(4 * e + 3)] = make_float2(r.w, i.w);
    }
    __syncthreads();

    // Layout A: idx = (m<<9)|(L<<3)|w -> cell(m) = phi(baseA) + (m<<9).
    const int addrA = phi((L << 3) | w);
    // Layout B: idx = (w<<10)|(L<<4)|m -> cell(m) = (baseB ^ (L&15)) ^ m.
    const int baseB  = (w << 10) | (L << 4);
    const int addrB0 = baseB ^ (L & 15);

    // Precomputed ds_bpermute lane addresses for the 5 exchange masks.
    int bpa[5];
    #pragma unroll
    for (int q = 0; q < 5; ++q) bpa[q] = (L ^ (32 >> q)) << 2;

    float2 v[16];

    for (int l = 0; l < LAYERS; ++l) {
        const float* gl = g + 4 * NTOT * l;   // wave-uniform -> s_load

        // READ_A (thread-private cells; RMW => no barrier before WRITE_A)
        #pragma unroll
        for (int m = 0; m < 16; ++m) v[m] = s[addrA + (m << 9)];

        // q0..q3: register bits (idx bits 12..9 = m bits 3..0)
        #pragma unroll
        for (int q = 0; q < 4; ++q) {
            const float A = gl[4 * q], B = gl[4 * q + 1];
            const float C = gl[4 * q + 2], D = gl[4 * q + 3];
            const int bit = 8 >> q;
            #pragma unroll
            for (int m = 0; m < 16; ++m)
                if (!(m & bit)) gate_pair(v[m], v[m | bit], A, B, C, D);
        }

        // q4..q8: lane bits (idx bit 12-q = L bit 9-q), partner via ds_bpermute.
        // bit=0 amp: new = (A+iB)v + (-C-iD)p ; bit=1 amp: new = (C-iD)p + (A-iB)v
        #pragma unroll
        for (int q = 4; q < 9; ++q) {
            const float A = gl[4 * q], B = gl[4 * q + 1];
            const float C = gl[4 * q + 2], D = gl[4 * q + 3];
            const int sh = 9 - q;            // L bit position: 5,4,3,2,1
            const int bit = (L >> sh) & 1;
            const int ba  = bpa[q - 4];
            const float Bs = bit ? -B : B;
            const float Cq = bit ? C : -C;
            #pragma unroll
            for (int m = 0; m < 16; ++m) {
                float vr = v[m].x, vi = v[m].y;
                float pr = __int_as_float(__builtin_amdgcn_ds_bpermute(ba, __float_as_int(vr)));
                float pi = __int_as_float(__builtin_amdgcn_ds_bpermute(ba, __float_as_int(vi)));
                v[m].x = A * vr - Bs * vi + Cq * pr + D * pi;
                v[m].y = A * vi + Bs * vr + Cq * pi - D * pr;
            }
        }

        // WRITE_A (same cells) -> barrier -> READ_B
        #pragma unroll
        for (int m = 0; m < 16; ++m) s[addrA + (m << 9)] = v[m];
        __syncthreads();
        #pragma unroll
        for (int m = 0; m < 16; ++m) v[m] = s[addrB0 ^ m];

        // q9..q12: register bits in layout B (idx bits 3..0 = m bits 3..0)
        #pragma unroll
        for (int q = 9; q < 13; ++q) {
            const float A = gl[4 * q], B = gl[4 * q + 1];
            const float C = gl[4 * q + 2], D = gl[4 * q + 3];
            const int bit = 8 >> (q - 9);
            #pragma unroll
            for (int m = 0; m < 16; ++m)
                if (!(m & bit)) gate_pair(v[m], v[m | bit], A, B, C, D);
        }

        // brickwork-CZ sign: (-1)^popc(idx & idx>>1), idx = baseB|m
        #pragma unroll
        for (int m = 0; m < 16; ++m) {
            int idx = baseB | m;
            float sg = 1.0f - 2.0f * (float)(__popc(idx & (idx >> 1)) & 1);
            v[m].x *= sg;
            v[m].y *= sg;
        }

        if (l < LAYERS - 1) {
            // WRITE_B (same cells RMW) -> barrier -> next layer's READ_A
            #pragma unroll
            for (int m = 0; m < 16; ++m) s[addrB0 ^ m] = v[m];
            __syncthreads();
        }
    }

    // ---- epilogue directly from layout-B registers (idx bit12 = w bit2 = ancilla)
    const int keep = (m_res[b] != 0) ? 1 : 0;
    const bool mine = ((w >> 2) & 1) == keep;
    float acc = 0.0f;
    #pragma unroll
    for (int m = 0; m < 16; ++m) acc += v[m].x * v[m].x + v[m].y * v[m].y;
    #pragma unroll
    for (int o = 32; o > 0; o >>= 1) acc += __shfl_down(acc, o, 64);
    __syncthreads();                    // all READ_Bs done; s[] reusable as scratch
    float* red = reinterpret_cast<float*>(s);
    if (L == 0) red[w] = acc;
    __syncthreads();
    const float tot = red[keep * 4 + 0] + red[keep * 4 + 1]
                    + red[keep * 4 + 2] + red[keep * 4 + 3];
    const float sc = rsqrtf(tot);
    if (mine) {
        const int j = ((w & 3) << 10) | (L << 4);   // output data index base (+m)
        float4* o4 = reinterpret_cast<float4*>(out + (size_t)b * DDATA * 2 + (size_t)j * 2);
        #pragma unroll
        for (int m = 0; m < 8; ++m)
            o4[m] = make_float4(v[2 * m].x * sc, v[2 * m].y * sc,
                                v[2 * m + 1].x * sc, v[2 * m + 1].y * sc);
    }
}

extern "C" void kernel_launch(void* const* d_in, const int* in_sizes, int n_in,
                              void* d_out, int out_size, void* d_ws, size_t ws_size,
                              hipStream_t stream) {
    const float* re     = (const float*)d_in[0];
    const float* im     = (const float*)d_in[1];
    const float* params = (const float*)d_in[2];
    const int*   mres   = (const int*)d_in[3];
    float* out   = (float*)d_out;
    float* gates = (float*)d_ws;   // 78*4 floats = 1248 B

    const int B = in_sizes[3];     // 512

    gates_precompute<<<1, 128, 0, stream>>>(params, gates);
    qddpm_main<<<B, BLOCK, 0, stream>>>(re, im, mres, gates, out);
}